// Round 4
// baseline (854.972 us; speedup 1.0000x reference)
//
#include <hip/hip_runtime.h>
#include <hip/hip_bf16.h>
#include <hip/hip_fp8.h>

// CrossViewContrast: loss = -mean_i( 2*<z1n_i,z2n_i> - log(sum_j exp(2*<z1n_i,z2n_j>) + 1e-8) )
// N=16384, D=128.
// R8 (best): MX-fp8 K=128 MFMA, 3 kernels, launch_bounds(256,8): sim 47.7us, total 111.5.
// R11: R8 + stride-4 granule placement -> SQ_LDS_BANK_CONFLICT == 0. sim 47.5, total 112.2.
// R12: JCHUNK 32->64 (fewer barriers): NULL (48.5). Barrier-count theory falsified.
// R13: 2-deep pacc + manual jj-prefetch: REGRESSED (55.4) = scratch spills (WRITE 35MB).
// R14: counted-vmcnt w/ runtime buffer rotation: REGRESSED (66.2) = worse spills
//   (FETCH 60MB / WRITE 76MB; cold dispatch 147us = scratch first-touch). The
//   launch_bounds(256,8) VGPR cap is 64/wave; any runtime-indexed state spills.
//   Pipeline mechanism NEVER actually tested in either attempt.
// R15: same T4 pipeline, register-safe: FULL UNROLL of the 32-chunk loop so every
//   buffer index/address is compile-time (rule #20); per-thread gsrc/ldst bases
//   precomputed so each STAGE is one immediate-folded add; stage-AFTER-barrier
//   ordering; explicit lgkmcnt(0) before each raw barrier (replaces the drain
//   __syncthreads provided) so a wave's ds_reads are in registers before any other
//   wave's DMA can overwrite that buffer. vmcnt(1) waits on a load issued 2 chunks
//   (~1000cyc) ago -> HBM misses landed; prefetch never drains in main loop.
//   VALU floor ~23.5us (16 exp2 x 8cyc trans + ~46 VALU x 2cyc per chunk-wave).
//   Predict: WRITE back to ~4MB (spill gate), sim -> 36-41us, MfmaUtil -> 33-38,
//   VALUBusy -> 62-70. If clean counters but sim >= 45: drain theory dead, attack
//   VALU work next.

#define N_ROWS 16384
#define DIM 128
#define JSPLIT 16
#define COLS_PER_BLOCK (N_ROWS / JSPLIT)   // 1024
#define JCHUNK 32
#define NCHUNK (COLS_PER_BLOCK / JCHUNK)   // 32
#define ROWS_PER_BLOCK 128
#define ITILES (N_ROWS / ROWS_PER_BLOCK)   // 128
#define GRID_TOTAL (ITILES * JSPLIT)       // 2048

// exp(2*sim) = 2^(SCALE*sim); SCALE baked into z1q so MFMA acc is already log2-domain.
#define SCALE 2.8853900817779268f  // 2 * log2(e)

typedef __attribute__((ext_vector_type(8))) int   int8v;   // v8i32: 32 fp8 bytes (MFMA A/B frag)
typedef __attribute__((ext_vector_type(4))) int   int4v;   // one 16B LDS granule
typedef __attribute__((ext_vector_type(4))) float floatx4; // MFMA C/D frag

#if __has_builtin(__builtin_amdgcn_exp2f)
#define EXP2(x) __builtin_amdgcn_exp2f(x)
#else
#define EXP2(x) exp2f(x)
#endif

// fmt 0 = OCP e4m3 for both A and B; scales = e8m0 1.0 in all bytes (identity).
__device__ inline floatx4 mfma_fp8_k128(int8v a, int8v b, floatx4 c) {
  return __builtin_amdgcn_mfma_scale_f32_16x16x128_f8f6f4(
      a, b, c, 0, 0, 0, 0x7F7F7F7F, 0, 0x7F7F7F7F);
}

__device__ inline void gload_lds16(const void* gptr, void* lptr) {
  __builtin_amdgcn_global_load_lds(
      (const __attribute__((address_space(1))) void*)gptr,
      (__attribute__((address_space(3))) void*)lptr, 16, 0, 0);
}

__device__ inline short pack_fp8x2(float x, float y) {
#if __has_builtin(__builtin_amdgcn_cvt_pk_fp8_f32)
  int p = __builtin_amdgcn_cvt_pk_fp8_f32(x, y, 0, false);  // bytes 0,1 of result
  return (short)(p & 0xFFFF);
#else
  __hip_fp8_e4m3 a(x), b(y);
  return (short)((unsigned char)a.__x | ((unsigned short)(unsigned char)b.__x << 8));
#endif
}

// ---------------- Kernel 1: row norms + diagonal + fp8 cast + zero init -----
__global__ __launch_bounds__(256) void norm_kernel(
    const float* __restrict__ z1, const float* __restrict__ z2,
    unsigned char* __restrict__ z1q, unsigned char* __restrict__ z2q,
    float* __restrict__ diag, float* __restrict__ denom,
    float* __restrict__ out) {
  int tid = threadIdx.x;
  int wave = tid >> 6, lane = tid & 63;
  int row = blockIdx.x * 4 + wave;   // one wave per row
  const float2* p1 = (const float2*)(z1 + (size_t)row * DIM);
  const float2* p2 = (const float2*)(z2 + (size_t)row * DIM);
  float2 a = p1[lane], b = p2[lane];
  float s11 = a.x * a.x + a.y * a.y;
  float s22 = b.x * b.x + b.y * b.y;
  float s12 = a.x * b.x + a.y * b.y;
#pragma unroll
  for (int m = 32; m >= 1; m >>= 1) {
    s11 += __shfl_xor(s11, m);
    s22 += __shfl_xor(s22, m);
    s12 += __shfl_xor(s12, m);
  }
  float inv1 = 1.0f / fmaxf(sqrtf(s11), 1e-12f);  // torch F.normalize eps
  float inv2 = 1.0f / fmaxf(sqrtf(s22), 1e-12f);
  float sc1 = inv1 * SCALE;                        // bake exp scale into A side
  // fp8 e4m3 (OCP on gfx950): |z1q| <= SCALE ~ 2.89 << 448 max. k order: 2*lane, 2*lane+1.
  ((short*)(z1q + (size_t)row * DIM))[lane] = pack_fp8x2(a.x * sc1, a.y * sc1);
  ((short*)(z2q + (size_t)row * DIM))[lane] = pack_fp8x2(b.x * inv2, b.y * inv2);
  if (lane == 0) {
    diag[row]  = s12 * inv1 * inv2;  // exact fp32 diagonal
    denom[row] = 0.0f;
  }
  if (blockIdx.x == 0 && tid == 0) out[0] = 0.0f;
}

// ---------------- Kernel 2: denom_i += sum_j exp(2*sim_ij), MX-fp8 MFMA -----
// Granule placement: logical granule o of row r stored at physical perm(o)^(r&7),
// perm(o)=(o>>1)|((o&1)<<2). Read (lane q,l15): lo at (q^s), hi at (q^s)^4 ->
// successive ds_read_b128s hit bank-groups 4 apart; R10/R11 measured
// SQ_LDS_BANK_CONFLICT == 0 with this layout.
__global__ __launch_bounds__(256, 8) void sim_kernel(
    const unsigned char* __restrict__ z1q,
    const unsigned char* __restrict__ z2q,
    float* __restrict__ denom) {
  __shared__ int4v lds[3][JCHUNK * 8];  // 3 x 4 KB (triple buffer, prefetch depth 2)

  int tid = threadIdx.x;
  int w   = tid >> 6;
  int q   = (tid >> 4) & 3;   // quad within wave
  int l15 = tid & 15;
  int s   = l15 & 7;          // swizzle key
  int itile  = blockIdx.x & (ITILES - 1);
  int jsplit = blockIdx.x >> 7;
  int i0 = itile * ROWS_PER_BLOCK + w * 32;

  const floatx4 ZERO4 = {0.f, 0.f, 0.f, 0.f};

  // A fragments: lane (q,l15) holds bytes [q*32, q*32+32) of row (i0+ii*16+l15).
  int8v afrag[2];
#pragma unroll
  for (int ii = 0; ii < 2; ++ii) {
    const int4v* rp = (const int4v*)(z1q + (size_t)(i0 + ii * 16 + l15) * DIM);
    int4v a0 = rp[q * 2], a1 = rp[q * 2 + 1];
    int8v af;
    af[0] = a0[0]; af[1] = a0[1]; af[2] = a0[2]; af[3] = a0[3];
    af[4] = a1[0]; af[5] = a1[1]; af[6] = a1[2]; af[7] = a1[3];
    afrag[ii] = af;
  }

  floatx4 rowsum[2];
  rowsum[0] = ZERO4;
  rowsum[1] = ZERO4;
  // carried accumulator; seed -1e30 so the first flush adds exp2(-1e30) = 0
  floatx4 pacc = {-1e30f, -1e30f, -1e30f, -1e30f};
  int psel = 1;  // which rowsum the pending pacc belongs to

  const char* Bbase = (const char*)z2q + (size_t)jsplit * COLS_PER_BLOCK * DIM;

  // Per-thread staging bases (loop-invariant): global source carries the inverse
  // granule permutation; LDS dest is lane-linear (gload_lds constraint).
  //   u = gl ^ (row&7); o = 2*(u&3) + (u>>2)
  {
  }
  int _row = tid >> 3, _gl = tid & 7;
  int _u = _gl ^ (_row & 7);
  int _o = 2 * (_u & 3) + (_u >> 2);
  const char* gsrc = Bbase + (size_t)_row * DIM + _o * 16;
  char* ldst = (char*)&lds[0][0] + (size_t)tid * 16;

  // one gload_lds16 per thread per chunk; addresses are base + compile-time offset
#define STAGE(cidx, bufi)                                                     \
  gload_lds16(gsrc + (size_t)(cidx) * (JCHUNK * DIM),                         \
              ldst + (size_t)(bufi) * (JCHUNK * 8 * 16))

  // Prologue: fill depth-2 pipeline (no waits -- first wait is in iteration 0).
  STAGE(0, 0);
  STAGE(1, 1);

  int lo_i = q ^ s;       // physical granule of logical 2q
  int hi_i = lo_i ^ 4;    // physical granule of logical 2q+1 (stride-4 apart)

  // Fully unrolled pipeline: iteration c
  //   [wait: own ds_reads drained + chunk c's DMA landed] [barrier]
  //   [stage chunk c+2 into buf (c+2)%3 -- safe: that buf held chunk c-1, whose
  //    reads all waves completed before this barrier (lgkmcnt(0) guarantees the
  //    data is in registers, not just issued)] [compute chunk c]
  // vmcnt(1): chunks c (issued 2 bodies ago, ~1000cyc -- HBM miss landed) and c+1
  // outstanding; wait leaves c+1 (and the just-issued c+2) in flight.
#pragma unroll
  for (int c = 0; c < NCHUNK; ++c) {
    if (c == NCHUNK - 1)
      asm volatile("s_waitcnt vmcnt(0) lgkmcnt(0)" ::: "memory");
    else
      asm volatile("s_waitcnt vmcnt(1) lgkmcnt(0)" ::: "memory");
    __builtin_amdgcn_s_barrier();
    if (c + 2 < NCHUNK) STAGE(c + 2, (c + 2) % 3);
    const int4v* buf = &lds[c % 3][0];

#pragma unroll
    for (int jj = 0; jj < 2; ++jj) {
      int rbase = (jj * 16 + l15) * 8;
      int4v lo = buf[rbase + lo_i];
      int4v hi = buf[rbase + hi_i];
      int8v bf;
      bf[0] = lo[0]; bf[1] = lo[1]; bf[2] = lo[2]; bf[3] = lo[3];
      bf[4] = hi[0]; bf[5] = hi[1]; bf[6] = hi[2]; bf[7] = hi[3];

#pragma unroll
      for (int ii = 0; ii < 2; ++ii) {
        floatx4 nacc = mfma_fp8_k128(afrag[ii], bf, ZERO4);
        // flush the PREVIOUS tile's accumulator in this MFMA's shadow
        floatx4 e;
#pragma unroll
        for (int r = 0; r < 4; ++r) e[r] = EXP2(pacc[r]);
        rowsum[psel] += e;
        pacc = nacc;
        psel = ii;
      }
    }
  }
  // final flush
  {
    floatx4 e;
#pragma unroll
    for (int r = 0; r < 4; ++r) e[r] = EXP2(pacc[r]);
    rowsum[psel] += e;
  }

  // reduce the 16 column-partials (spread over l15) and commit.
  // C/D layout (shape-determined): col = lane&15 (j), row = q*4 + r (i).
#pragma unroll
  for (int ii = 0; ii < 2; ++ii)
#pragma unroll
    for (int r = 0; r < 4; ++r) {
      float v = rowsum[ii][r];
      v += __shfl_xor(v, 1);
      v += __shfl_xor(v, 2);
      v += __shfl_xor(v, 4);
      v += __shfl_xor(v, 8);
      if (l15 == 0) atomicAdd(&denom[i0 + ii * 16 + q * 4 + r], v);
    }
}

// ---------------- Kernel 3: loss = -mean(2*diag - log(denom+eps)) -----------
// 64 blocks x 256 threads; one row/thread; wave-reduce then one atomicAdd/wave.
__global__ __launch_bounds__(256) void loss_kernel(
    const float* __restrict__ denom, const float* __restrict__ diag,
    float* __restrict__ out) {
  int row = blockIdx.x * 256 + threadIdx.x;
  float t = 2.0f * diag[row] - __logf(denom[row] + 1e-8f);
#pragma unroll
  for (int m = 32; m >= 1; m >>= 1) t += __shfl_xor(t, m);
  if ((threadIdx.x & 63) == 0) atomicAdd(out, -t * (1.0f / N_ROWS));
}

extern "C" void kernel_launch(void* const* d_in, const int* in_sizes, int n_in,
                              void* d_out, int out_size, void* d_ws, size_t ws_size,
                              hipStream_t stream) {
  const float* z1 = (const float*)d_in[0];
  const float* z2 = (const float*)d_in[1];
  char* ws = (char*)d_ws;
  unsigned char* z1q = (unsigned char*)ws;                                  // 2 MB
  unsigned char* z2q = (unsigned char*)(ws + (size_t)N_ROWS * DIM);         // 2 MB
  float* denom = (float*)(ws + (size_t)2 * N_ROWS * DIM);                   // 64 KB
  float* diag  = (float*)(ws + (size_t)2 * N_ROWS * DIM + (size_t)N_ROWS * 4);
  float* outp  = (float*)d_out;

  norm_kernel<<<N_ROWS / 4, 256, 0, stream>>>(z1, z2, z1q, z2q, diag, denom, outp);
  sim_kernel<<<GRID_TOTAL, 256, 0, stream>>>(z1q, z2q, denom);
  loss_kernel<<<N_ROWS / 256, 256, 0, stream>>>(denom, diag, outp);
}

// Round 5
// 110.689 us; speedup vs baseline: 7.7241x; 7.7241x over previous
//
#include <hip/hip_runtime.h>
#include <hip/hip_bf16.h>
#include <hip/hip_fp8.h>

// CrossViewContrast: loss = -mean_i( 2*<z1n_i,z2n_i> - log(sum_j exp(2*<z1n_i,z2n_j>) + 1e-8) )
// N=16384, D=128.
// R8 (best): MX-fp8 K=128 MFMA, 3 kernels, launch_bounds(256,8): sim 47.7us, total 111.5.
// R11: R8 + stride-4 granule placement -> SQ_LDS_BANK_CONFLICT == 0. sim 47.5, total 112.2.
// R12: JCHUNK 32->64 (fewer barriers): NULL (48.5). Barrier-count theory falsified.
// R13: 2-deep pacc + manual jj-prefetch @(256,8): REGRESSED (55.4) -- spills (WRITE 35MB).
// R14: counted-vmcnt runtime-rotation @(256,8): REGRESSED (66.2) -- spills (WRITE 76MB).
// R15: counted-vmcnt full-unroll @(256,8): CATASTROPHE (796us, WRITE 1.8GB) -- the 32x
//   unroll hoisted per-chunk addresses/state past the 64-VGPR cap; spill-fill loops.
//   LESSON: every structural attempt died on the (256,8) 64-VGPR ceiling; none tested
//   its mechanism. Trace VGPR_Count=32 is unreliable when spilling.
// R16: buy headroom, test the cheapest mechanism. R11's measured occupancy was only
//   ~51% (~4 waves/SIMD) despite (256,8), so relaxing to __launch_bounds__(256,4)
//   (128-VGPR cap) costs ~nothing in real residency but removes the spill cliff.
//   On top of byte-identical R11 structure: 2-deep flush pacc[ii] (static index) --
//   each ii slot flushes its own previous MFMA, 2 tile-steps (~110+cyc) old vs 1
//   (~40cyc vs ~64-70cyc scaled-MFMA latency). psel deleted. NO other changes.
//   Predict: WRITE ~4MB / FETCH ~9-11MB (spill gate), sim -> 38-43us, MfmaUtil 31-36,
//   VALUBusy 58-66, conflicts 0. If clean but sim ~47-50: dep-chain theory dead too;
//   attack VALU work next. If sim >= 55 clean: occupancy was binding; revert bound.

#define N_ROWS 16384
#define DIM 128
#define JSPLIT 16
#define COLS_PER_BLOCK (N_ROWS / JSPLIT)   // 1024
#define JCHUNK 32
#define NCHUNK (COLS_PER_BLOCK / JCHUNK)   // 32
#define ROWS_PER_BLOCK 128
#define ITILES (N_ROWS / ROWS_PER_BLOCK)   // 128
#define GRID_TOTAL (ITILES * JSPLIT)       // 2048

// exp(2*sim) = 2^(SCALE*sim); SCALE baked into z1q so MFMA acc is already log2-domain.
#define SCALE 2.8853900817779268f  // 2 * log2(e)

typedef __attribute__((ext_vector_type(8))) int   int8v;   // v8i32: 32 fp8 bytes (MFMA A/B frag)
typedef __attribute__((ext_vector_type(4))) int   int4v;   // one 16B LDS granule
typedef __attribute__((ext_vector_type(4))) float floatx4; // MFMA C/D frag

#if __has_builtin(__builtin_amdgcn_exp2f)
#define EXP2(x) __builtin_amdgcn_exp2f(x)
#else
#define EXP2(x) exp2f(x)
#endif

// fmt 0 = OCP e4m3 for both A and B; scales = e8m0 1.0 in all bytes (identity).
__device__ inline floatx4 mfma_fp8_k128(int8v a, int8v b, floatx4 c) {
  return __builtin_amdgcn_mfma_scale_f32_16x16x128_f8f6f4(
      a, b, c, 0, 0, 0, 0x7F7F7F7F, 0, 0x7F7F7F7F);
}

__device__ inline void gload_lds16(const void* gptr, void* lptr) {
  __builtin_amdgcn_global_load_lds(
      (const __attribute__((address_space(1))) void*)gptr,
      (__attribute__((address_space(3))) void*)lptr, 16, 0, 0);
}

__device__ inline short pack_fp8x2(float x, float y) {
#if __has_builtin(__builtin_amdgcn_cvt_pk_fp8_f32)
  int p = __builtin_amdgcn_cvt_pk_fp8_f32(x, y, 0, false);  // bytes 0,1 of result
  return (short)(p & 0xFFFF);
#else
  __hip_fp8_e4m3 a(x), b(y);
  return (short)((unsigned char)a.__x | ((unsigned short)(unsigned char)b.__x << 8));
#endif
}

// ---------------- Kernel 1: row norms + diagonal + fp8 cast + zero init -----
__global__ __launch_bounds__(256) void norm_kernel(
    const float* __restrict__ z1, const float* __restrict__ z2,
    unsigned char* __restrict__ z1q, unsigned char* __restrict__ z2q,
    float* __restrict__ diag, float* __restrict__ denom,
    float* __restrict__ out) {
  int tid = threadIdx.x;
  int wave = tid >> 6, lane = tid & 63;
  int row = blockIdx.x * 4 + wave;   // one wave per row
  const float2* p1 = (const float2*)(z1 + (size_t)row * DIM);
  const float2* p2 = (const float2*)(z2 + (size_t)row * DIM);
  float2 a = p1[lane], b = p2[lane];
  float s11 = a.x * a.x + a.y * a.y;
  float s22 = b.x * b.x + b.y * b.y;
  float s12 = a.x * b.x + a.y * b.y;
#pragma unroll
  for (int m = 32; m >= 1; m >>= 1) {
    s11 += __shfl_xor(s11, m);
    s22 += __shfl_xor(s22, m);
    s12 += __shfl_xor(s12, m);
  }
  float inv1 = 1.0f / fmaxf(sqrtf(s11), 1e-12f);  // torch F.normalize eps
  float inv2 = 1.0f / fmaxf(sqrtf(s22), 1e-12f);
  float sc1 = inv1 * SCALE;                        // bake exp scale into A side
  // fp8 e4m3 (OCP on gfx950): |z1q| <= SCALE ~ 2.89 << 448 max. k order: 2*lane, 2*lane+1.
  ((short*)(z1q + (size_t)row * DIM))[lane] = pack_fp8x2(a.x * sc1, a.y * sc1);
  ((short*)(z2q + (size_t)row * DIM))[lane] = pack_fp8x2(b.x * inv2, b.y * inv2);
  if (lane == 0) {
    diag[row]  = s12 * inv1 * inv2;  // exact fp32 diagonal
    denom[row] = 0.0f;
  }
  if (blockIdx.x == 0 && tid == 0) out[0] = 0.0f;
}

// ---------------- Kernel 2: denom_i += sum_j exp(2*sim_ij), MX-fp8 MFMA -----
// Granule placement: logical granule o of row r stored at physical perm(o)^(r&7),
// perm(o)=(o>>1)|((o&1)<<2). Read (lane q,l15): lo at (q^s), hi at (q^s)^4 ->
// successive ds_read_b128s hit bank-groups 4 apart; R10/R11 measured
// SQ_LDS_BANK_CONFLICT == 0 with this layout.
__global__ __launch_bounds__(256, 4) void sim_kernel(
    const unsigned char* __restrict__ z1q,
    const unsigned char* __restrict__ z2q,
    float* __restrict__ denom) {
  __shared__ int4v lds[2][JCHUNK * 8];  // 2 x 4 KB

  int tid = threadIdx.x;
  int w   = tid >> 6;
  int q   = (tid >> 4) & 3;   // quad within wave
  int l15 = tid & 15;
  int s   = l15 & 7;          // swizzle key
  int itile  = blockIdx.x & (ITILES - 1);
  int jsplit = blockIdx.x >> 7;
  int i0 = itile * ROWS_PER_BLOCK + w * 32;

  const floatx4 ZERO4 = {0.f, 0.f, 0.f, 0.f};

  // A fragments: lane (q,l15) holds bytes [q*32, q*32+32) of row (i0+ii*16+l15).
  int8v afrag[2];
#pragma unroll
  for (int ii = 0; ii < 2; ++ii) {
    const int4v* rp = (const int4v*)(z1q + (size_t)(i0 + ii * 16 + l15) * DIM);
    int4v a0 = rp[q * 2], a1 = rp[q * 2 + 1];
    int8v af;
    af[0] = a0[0]; af[1] = a0[1]; af[2] = a0[2]; af[3] = a0[3];
    af[4] = a1[0]; af[5] = a1[1]; af[6] = a1[2]; af[7] = a1[3];
    afrag[ii] = af;
  }

  floatx4 rowsum[2];
  rowsum[0] = ZERO4;
  rowsum[1] = ZERO4;
  // 2-deep carried accumulators, one per ii slot (tiles alternate ii=0,1 so the
  // slot's previous MFMA is 2 tile-steps old when flushed -> latency hidden).
  // Static indexing only (pacc[ii] with compile-time ii after unroll).
  floatx4 pacc0 = {-1e30f, -1e30f, -1e30f, -1e30f};
  floatx4 pacc1 = {-1e30f, -1e30f, -1e30f, -1e30f};

  const char* Bbase = (const char*)z2q + (size_t)jsplit * COLS_PER_BLOCK * DIM;

  // stage one 4 KB chunk: 256 thr x 16 B, lane-linear LDS dest (constraint).
  // physical slot gl of row holds logical o = inv_perm(gl ^ (row&7)):
  //   u = gl ^ (row&7); o = 2*(u&3) + (u>>2)
#define STAGE(cidx, bufi)                                                    \
  do {                                                                       \
    const char* _ck = Bbase + (size_t)(cidx) * JCHUNK * DIM;                 \
    char* _dst = (char*)&lds[bufi][0];                                       \
    int _row = tid >> 3, _gl = tid & 7;                                      \
    int _u = _gl ^ (_row & 7);                                               \
    int _o = 2 * (_u & 3) + (_u >> 2);                                       \
    gload_lds16(_ck + (size_t)_row * DIM + _o * 16,                          \
                _dst + (size_t)tid * 16);                                    \
  } while (0)

  STAGE(0, 0);
  __syncthreads();

  int lo_i = q ^ s;       // physical granule of logical 2q
  int hi_i = lo_i ^ 4;    // physical granule of logical 2q+1 (stride-4 apart)

  for (int c = 0; c < NCHUNK; ++c) {
    if (c + 1 < NCHUNK) STAGE(c + 1, (c + 1) & 1);
    const int4v* buf = &lds[c & 1][0];

#pragma unroll
    for (int jj = 0; jj < 2; ++jj) {
      int rbase = (jj * 16 + l15) * 8;
      int4v lo = buf[rbase + lo_i];
      int4v hi = buf[rbase + hi_i];
      int8v bf;
      bf[0] = lo[0]; bf[1] = lo[1]; bf[2] = lo[2]; bf[3] = lo[3];
      bf[4] = hi[0]; bf[5] = hi[1]; bf[6] = hi[2]; bf[7] = hi[3];

      // ii = 0: flush slot 0's previous tile (2 tile-steps old)
      {
        floatx4 nacc = mfma_fp8_k128(afrag[0], bf, ZERO4);
        floatx4 e;
#pragma unroll
        for (int r = 0; r < 4; ++r) e[r] = EXP2(pacc0[r]);
        rowsum[0] += e;
        pacc0 = nacc;
      }
      // ii = 1: flush slot 1's previous tile (2 tile-steps old)
      {
        floatx4 nacc = mfma_fp8_k128(afrag[1], bf, ZERO4);
        floatx4 e;
#pragma unroll
        for (int r = 0; r < 4; ++r) e[r] = EXP2(pacc1[r]);
        rowsum[1] += e;
        pacc1 = nacc;
      }
    }
    __syncthreads();  // guards buf reuse
  }
  // final flush of both slots
  {
    floatx4 e;
#pragma unroll
    for (int r = 0; r < 4; ++r) e[r] = EXP2(pacc0[r]);
    rowsum[0] += e;
#pragma unroll
    for (int r = 0; r < 4; ++r) e[r] = EXP2(pacc1[r]);
    rowsum[1] += e;
  }

  // reduce the 16 column-partials (spread over l15) and commit.
  // C/D layout (shape-determined): col = lane&15 (j), row = q*4 + r (i).
#pragma unroll
  for (int ii = 0; ii < 2; ++ii)
#pragma unroll
    for (int r = 0; r < 4; ++r) {
      float v = rowsum[ii][r];
      v += __shfl_xor(v, 1);
      v += __shfl_xor(v, 2);
      v += __shfl_xor(v, 4);
      v += __shfl_xor(v, 8);
      if (l15 == 0) atomicAdd(&denom[i0 + ii * 16 + q * 4 + r], v);
    }
}

// ---------------- Kernel 3: loss = -mean(2*diag - log(denom+eps)) -----------
// 64 blocks x 256 threads; one row/thread; wave-reduce then one atomicAdd/wave.
__global__ __launch_bounds__(256) void loss_kernel(
    const float* __restrict__ denom, const float* __restrict__ diag,
    float* __restrict__ out) {
  int row = blockIdx.x * 256 + threadIdx.x;
  float t = 2.0f * diag[row] - __logf(denom[row] + 1e-8f);
#pragma unroll
  for (int m = 32; m >= 1; m >>= 1) t += __shfl_xor(t, m);
  if ((threadIdx.x & 63) == 0) atomicAdd(out, -t * (1.0f / N_ROWS));
}

extern "C" void kernel_launch(void* const* d_in, const int* in_sizes, int n_in,
                              void* d_out, int out_size, void* d_ws, size_t ws_size,
                              hipStream_t stream) {
  const float* z1 = (const float*)d_in[0];
  const float* z2 = (const float*)d_in[1];
  char* ws = (char*)d_ws;
  unsigned char* z1q = (unsigned char*)ws;                                  // 2 MB
  unsigned char* z2q = (unsigned char*)(ws + (size_t)N_ROWS * DIM);         // 2 MB
  float* denom = (float*)(ws + (size_t)2 * N_ROWS * DIM);                   // 64 KB
  float* diag  = (float*)(ws + (size_t)2 * N_ROWS * DIM + (size_t)N_ROWS * 4);
  float* outp  = (float*)d_out;

  norm_kernel<<<N_ROWS / 4, 256, 0, stream>>>(z1, z2, z1q, z2q, diag, denom, outp);
  sim_kernel<<<GRID_TOTAL, 256, 0, stream>>>(z1q, z2q, denom);
  loss_kernel<<<N_ROWS / 256, 256, 0, stream>>>(denom, diag, outp);
}